// Round 3
// baseline (645.513 us; speedup 1.0000x reference)
//
#include <hip/hip_runtime.h>
#include <hip/hip_bf16.h>

typedef __hip_bfloat16 bf16;
typedef unsigned short u16;

#define NC 8192
#define NF 32768
#define DD 256
#define DE 128
#define KNN 16
#define FMAXV 3.402823466e+38f

__device__ __forceinline__ float bfbits2f(u16 u){
  union { unsigned u; float f; } x; x.u = ((unsigned)u) << 16; return x.f;
}

// ---------- decoder positions -> float4(x,y,z,|d|^2) ----------
__global__ __launch_bounds__(256) void k_pos4(const float* __restrict__ dpos,
                                              float4* __restrict__ pos4){
  int i = blockIdx.x * 256 + threadIdx.x;
  if (i < NC){
    float x = dpos[i * 3 + 0], y = dpos[i * 3 + 1], z = dpos[i * 3 + 2];
    float dd = __fadd_rn(__fadd_rn(__fmul_rn(x,x), __fmul_rn(y,y)), __fmul_rn(z,z));
    pos4[i] = make_float4(x, y, z, dd);
  }
}

// ---------- decoder tables: K=df@Wk^T+bk, V=df@Wv^T+bv (LDS only),
//            then Zd = K@Wq [*,128], Ud = V@W1a^T [*,128], bqK = K.bq ----------
__global__ __launch_bounds__(256) void k_dec(const float* __restrict__ df,
                                             const float* __restrict__ Wq, const float* __restrict__ bq,
                                             const float* __restrict__ Wk, const float* __restrict__ bk,
                                             const float* __restrict__ Wv, const float* __restrict__ bv,
                                             const float* __restrict__ W1,
                                             bf16* __restrict__ Zd, bf16* __restrict__ Ud,
                                             float* __restrict__ bqK){
  __shared__ float bufA[16 * 256];   // df staging, then K rows
  __shared__ float bufB[16 * 256];   // V rows
  int t = threadIdx.x;
  int g0 = blockIdx.x * 16;
  for (int r = 0; r < 16; ++r)
    bufA[r * 256 + t] = df[(size_t)(g0 + r) * 256 + t];
  __syncthreads();
  float accK[16], accV[16];
  #pragma unroll
  for (int p = 0; p < 16; ++p){ accK[p] = 0.f; accV[p] = 0.f; }
  const float4* wkp = (const float4*)(Wk + (size_t)t * 256);
  const float4* wvp = (const float4*)(Wv + (size_t)t * 256);
  const float4* A4 = (const float4*)bufA;
  for (int c4 = 0; c4 < 64; ++c4){
    float4 wk = wkp[c4], wv = wvp[c4];
    #pragma unroll
    for (int p = 0; p < 16; ++p){
      float4 a = A4[p * 64 + c4];
      accK[p] += wk.x*a.x + wk.y*a.y + wk.z*a.z + wk.w*a.w;
      accV[p] += wv.x*a.x + wv.y*a.y + wv.z*a.z + wv.w*a.w;
    }
  }
  float bkj = bk[t];
  float bvj = bv[t];
  __syncthreads();                       // all df reads done; bufA can be overwritten
  #pragma unroll
  for (int p = 0; p < 16; ++p){
    bufA[p * 256 + t] = accK[p] + bkj;   // K
    bufB[p * 256 + t] = accV[p] + bvj;   // V
  }
  __syncthreads();
  // bqK (16 threads; bq is typically zero but keep exact)
  if (t < 16){
    float s = 0.f;
    for (int j = 0; j < 256; ++j) s += bq[j] * bufA[t * 256 + j];
    bqK[g0 + t] = s;
  }
  // Zd[p][c] = sum_j K[p][j] * Wq[j][c]   (c = t&127, 8 points per thread)
  {
    int c = t & 127, pg = t >> 7;
    float acc[8];
    #pragma unroll
    for (int pp = 0; pp < 8; ++pp) acc[pp] = 0.f;
    for (int j0 = 0; j0 < 256; j0 += 8){
      float w[8];
      #pragma unroll
      for (int jj = 0; jj < 8; ++jj)
        w[jj] = Wq[(size_t)(j0 + jj) * 128 + c];
      #pragma unroll
      for (int pp = 0; pp < 8; ++pp){
        float4 a = ((const float4*)bufA)[(pg * 8 + pp) * 64 + (j0 >> 2)];
        float4 b = ((const float4*)bufA)[(pg * 8 + pp) * 64 + (j0 >> 2) + 1];
        acc[pp] += w[0]*a.x + w[1]*a.y + w[2]*a.z + w[3]*a.w
                 + w[4]*b.x + w[5]*b.y + w[6]*b.z + w[7]*b.w;
      }
    }
    #pragma unroll
    for (int pp = 0; pp < 8; ++pp)
      Zd[(size_t)(g0 + pg * 8 + pp) * 128 + c] = __float2bfloat16(acc[pp]);
  }
  // Ud[p][h] = sum_c W1[h][c] * V[p][c]   (h = t&127, first 256 cols of W1)
  {
    int h = t & 127, pg = t >> 7;
    float acc[8];
    #pragma unroll
    for (int pp = 0; pp < 8; ++pp) acc[pp] = 0.f;
    const float4* w1r = (const float4*)(W1 + (size_t)h * 384);
    for (int c4 = 0; c4 < 64; ++c4){
      float4 w = w1r[c4];
      #pragma unroll
      for (int pp = 0; pp < 8; ++pp){
        float4 a = ((const float4*)bufB)[(pg * 8 + pp) * 64 + c4];
        acc[pp] += w.x*a.x + w.y*a.y + w.z*a.z + w.w*a.w;
      }
    }
    #pragma unroll
    for (int pp = 0; pp < 8; ++pp)
      Ud[(size_t)(g0 + pg * 8 + pp) * 128 + h] = __float2bfloat16(acc[pp]);
  }
}

// ---------- fused: brute-force top-16 KNN + attention (via Zd) + hidden agg (via Ud) ----------
__global__ __launch_bounds__(256) void k_attn(const float* __restrict__ epos,
                                              const float4* __restrict__ pos4,
                                              const float* __restrict__ ef,
                                              const bf16* __restrict__ Zd,
                                              const bf16* __restrict__ Ud,
                                              const float* __restrict__ bqK,
                                              bf16* __restrict__ hagg){
  __shared__ float4 stage[1024];
  int t = threadIdx.x;
  int lane = t & 63;
  int n = blockIdx.x * 4 + (t >> 6);
  float ex = epos[n * 3 + 0], ey = epos[n * 3 + 1], ez = epos[n * 3 + 2];
  float ee = __fadd_rn(__fadd_rn(__fmul_rn(ex,ex), __fmul_rn(ey,ey)), __fmul_rn(ez,ez));

  float topv = FMAXV;
  int   topi = 0;
  float tau  = FMAXV;

  for (int ch = 0; ch < 8; ++ch){
    __syncthreads();
    #pragma unroll
    for (int u = 0; u < 4; ++u)
      stage[u * 256 + t] = pos4[ch * 1024 + u * 256 + t];
    __syncthreads();
    for (int s = 0; s < 16; ++s){
      float4 P = stage[s * 64 + lane];
      float ed = fmaf(ez, P.z, fmaf(ey, P.y, ex * P.x));
      float d2 = (ee - 2.f * ed) + P.w;
      int idx = ch * 1024 + s * 64 + lane;
      unsigned long long m = __ballot(d2 < tau);
      while (m){
        int src = __ffsll((unsigned long long)m) - 1;
        m &= m - 1;
        float v  = __shfl(d2, src);
        int   vi = __shfl(idx, src);
        if (v < tau){
          int pos = __popcll(__ballot((lane < KNN) && (topv <= v)));
          float sv = __shfl_up(topv, 1);
          int   si = __shfl_up(topi, 1);
          if (lane < KNN){
            if (lane == pos){ topv = v; topi = vi; }
            else if (lane > pos){ topv = sv; topi = si; }
          }
          tau = __shfl(topv, KNN - 1);
        }
      }
    }
  }

  // scores: sc_k = (ef[n] . Zd[ik] + bqK[ik]) / 16
  float2 eu = *(const float2*)(ef + (size_t)n * 128 + lane * 2);
  float sc = -FMAXV;
  #pragma unroll
  for (int k = 0; k < KNN; ++k){
    int ik = __shfl(topi, k);
    ushort2 zu = *(const ushort2*)((const u16*)Zd + (size_t)ik * 128 + lane * 2);
    float p = eu.x * bfbits2f(zu.x) + eu.y * bfbits2f(zu.y);
    #pragma unroll
    for (int off = 32; off >= 1; off >>= 1) p += __shfl_xor(p, off);
    float bz = bqK[ik];
    if (lane == k) sc = (p + bz) * (1.0f / 16.0f);
  }
  // softmax over lanes 0..15
  float mx = sc;
  #pragma unroll
  for (int off = 8; off >= 1; off >>= 1) mx = fmaxf(mx, __shfl_xor(mx, off));
  float e = (lane < KNN) ? __expf(sc - mx) : 0.f;
  float l = e;
  #pragma unroll
  for (int off = 8; off >= 1; off >>= 1) l += __shfl_xor(l, off);
  float wgt = (lane < KNN) ? (e / l) : 0.f;

  // hidden-space aggregation: hagg = sum_k w_k * Ud[ik]  (2 channels per lane)
  float a0 = 0.f, a1 = 0.f;
  #pragma unroll
  for (int k = 0; k < KNN; ++k){
    int ik = __shfl(topi, k);
    float wk = __shfl(wgt, k);
    ushort2 uu = *(const ushort2*)((const u16*)Ud + (size_t)ik * 128 + lane * 2);
    a0 = fmaf(wk, bfbits2f(uu.x), a0);
    a1 = fmaf(wk, bfbits2f(uu.y), a1);
  }
  bf16* hr = hagg + (size_t)n * 128 + lane * 2;
  hr[0] = __float2bfloat16(a0);
  hr[1] = __float2bfloat16(a1);
}

// ---------- MLP: h = relu(hagg + W1e@ef + b1); up = W2@h + b2; LayerNorm ----------
__global__ __launch_bounds__(256) void k_mlp(const bf16* __restrict__ hagg, const float* __restrict__ ef,
                                             const float* __restrict__ W1, const float* __restrict__ b1,
                                             const float* __restrict__ W2, const float* __restrict__ b2,
                                             const float* __restrict__ lng, const float* __restrict__ lnb,
                                             float* __restrict__ out){
  __shared__ float efs[16 * 128];
  __shared__ float hgs[16 * 128];
  __shared__ float hbuf[16 * 128];
  __shared__ float ubuf[16 * 128];
  __shared__ float stats[32];
  int t = threadIdx.x;
  int n0 = blockIdx.x * 16;
  for (int f = t; f < 2048; f += 256){
    int r = f >> 7, c = f & 127;
    efs[f] = ef[(size_t)(n0 + r) * 128 + c];
    hgs[f] = __bfloat162float(hagg[(size_t)(n0 + r) * 128 + c]);
  }
  __syncthreads();
  int jg = t & 63, pg = t >> 6;
  int j0 = jg * 2, p0 = pg * 4;
  float acc[2][4];
  #pragma unroll
  for (int a = 0; a < 2; ++a)
    #pragma unroll
    for (int p = 0; p < 4; ++p) acc[a][p] = 0.f;
  const float4* w1a = (const float4*)(W1 + (size_t)j0 * 384 + 256);
  const float4* w1b = (const float4*)(W1 + (size_t)(j0 + 1) * 384 + 256);
  const float4* efs4 = (const float4*)efs;
  for (int c4 = 0; c4 < 32; ++c4){
    float4 wa = w1a[c4], wb = w1b[c4];
    #pragma unroll
    for (int p = 0; p < 4; ++p){
      float4 x = efs4[(p0 + p) * 32 + c4];
      acc[0][p] += wa.x*x.x + wa.y*x.y + wa.z*x.z + wa.w*x.w;
      acc[1][p] += wb.x*x.x + wb.y*x.y + wb.z*x.z + wb.w*x.w;
    }
  }
  float b1a = b1[j0], b1b = b1[j0 + 1];
  #pragma unroll
  for (int p = 0; p < 4; ++p){
    hbuf[(p0 + p) * 128 + j0]     = fmaxf(acc[0][p] + b1a + hgs[(p0 + p) * 128 + j0],     0.f);
    hbuf[(p0 + p) * 128 + j0 + 1] = fmaxf(acc[1][p] + b1b + hgs[(p0 + p) * 128 + j0 + 1], 0.f);
  }
  __syncthreads();
  float acc2[2][4];
  #pragma unroll
  for (int a = 0; a < 2; ++a)
    #pragma unroll
    for (int p = 0; p < 4; ++p) acc2[a][p] = 0.f;
  const float4* w2a = (const float4*)(W2 + (size_t)j0 * 128);
  const float4* w2b = (const float4*)(W2 + (size_t)(j0 + 1) * 128);
  const float4* hb4 = (const float4*)hbuf;
  for (int c4 = 0; c4 < 32; ++c4){
    float4 wa = w2a[c4], wb = w2b[c4];
    #pragma unroll
    for (int p = 0; p < 4; ++p){
      float4 x = hb4[(p0 + p) * 32 + c4];
      acc2[0][p] += wa.x*x.x + wa.y*x.y + wa.z*x.z + wa.w*x.w;
      acc2[1][p] += wb.x*x.x + wb.y*x.y + wb.z*x.z + wb.w*x.w;
    }
  }
  float b2a = b2[j0], b2b = b2[j0 + 1];
  float u[2][4];
  #pragma unroll
  for (int p = 0; p < 4; ++p){
    u[0][p] = acc2[0][p] + b2a;
    u[1][p] = acc2[1][p] + b2b;
    ubuf[(p0 + p) * 128 + j0]     = u[0][p];
    ubuf[(p0 + p) * 128 + j0 + 1] = u[1][p];
  }
  __syncthreads();
  {
    int p = t >> 4, qi = t & 15;
    const float* ub = &ubuf[p * 128 + qi * 8];
    float s = 0.f, s2 = 0.f;
    #pragma unroll
    for (int e2i = 0; e2i < 8; ++e2i){ float v = ub[e2i]; s += v; s2 += v * v; }
    #pragma unroll
    for (int off = 1; off < 16; off <<= 1){ s += __shfl_xor(s, off); s2 += __shfl_xor(s2, off); }
    if (qi == 0){
      float mu = s * (1.f / 128.f);
      float var = s2 * (1.f / 128.f) - mu * mu;
      stats[p] = mu;
      stats[16 + p] = rsqrtf(fmaxf(var, 0.f) + 1e-5f);
    }
  }
  __syncthreads();
  float ga = lng[j0], gb = lng[j0 + 1];
  float ba = lnb[j0], bbv = lnb[j0 + 1];
  #pragma unroll
  for (int p = 0; p < 4; ++p){
    float mu = stats[p0 + p], rs = stats[16 + p0 + p];
    out[(size_t)(n0 + p0 + p) * 128 + j0]     = (u[0][p] - mu) * rs * ga + ba;
    out[(size_t)(n0 + p0 + p) * 128 + j0 + 1] = (u[1][p] - mu) * rs * gb + bbv;
  }
}

// ---------- passthrough outputs: encoder_pos and labels ----------
__global__ __launch_bounds__(256) void k_tail(const float* __restrict__ epos,
                                              const int* __restrict__ lab,
                                              float* __restrict__ out){
  int i = blockIdx.x * 256 + threadIdx.x;
  if (i < NF){
    float* op = out + (size_t)NF * 128;
    op[i * 3 + 0] = epos[i * 3 + 0];
    op[i * 3 + 1] = epos[i * 3 + 1];
    op[i * 3 + 2] = epos[i * 3 + 2];
    out[(size_t)NF * 128 + (size_t)NF * 3 + i] = (float)lab[i];
  }
}

extern "C" void kernel_launch(void* const* d_in, const int* in_sizes, int n_in,
                              void* d_out, int out_size, void* d_ws, size_t ws_size,
                              hipStream_t stream){
  const float* df   = (const float*)d_in[0];
  const float* dpos = (const float*)d_in[1];
  const float* ef   = (const float*)d_in[2];
  const float* epos = (const float*)d_in[3];
  const int*   lab  = (const int*)d_in[4];
  const float* Wq = (const float*)d_in[5];
  const float* bq = (const float*)d_in[6];
  const float* Wk = (const float*)d_in[7];
  const float* bk = (const float*)d_in[8];
  const float* Wv = (const float*)d_in[9];
  const float* bv = (const float*)d_in[10];
  const float* W1 = (const float*)d_in[11];
  const float* b1 = (const float*)d_in[12];
  const float* W2 = (const float*)d_in[13];
  const float* b2 = (const float*)d_in[14];
  const float* lng = (const float*)d_in[15];
  const float* lnb = (const float*)d_in[16];
  float* out = (float*)d_out;

  // workspace layout (total ~12.2 MB)
  char* wsb = (char*)d_ws;
  float4* pos4 = (float4*)wsb;                        // 131072 B
  bf16*  Zd   = (bf16*)(wsb + 131072);                // 2 MB
  bf16*  Ud   = (bf16*)(wsb + 131072 + 2097152);      // 2 MB
  float* bqK  = (float*)(wsb + 131072 + 4194304);     // 32 KB
  bf16*  hagg = (bf16*)(wsb + 131072 + 4194304 + 32768); // 8 MB

  k_pos4 <<<NC / 256, 256, 0, stream>>>(dpos, pos4);
  k_dec  <<<NC / 16,  256, 0, stream>>>(df, Wq, bq, Wk, bk, Wv, bv, W1, Zd, Ud, bqK);
  k_attn <<<NF / 4,   256, 0, stream>>>(epos, pos4, ef, Zd, Ud, bqK, hagg);
  k_mlp  <<<NF / 16,  256, 0, stream>>>(hagg, ef, W1, b1, W2, b2, lng, lnb, out);
  k_tail <<<NF / 256, 256, 0, stream>>>(epos, lab, out);
  (void)in_sizes; (void)n_in; (void)out_size; (void)ws_size;
}

// Round 4
// 538.812 us; speedup vs baseline: 1.1980x; 1.1980x over previous
//
#include <hip/hip_runtime.h>
#include <hip/hip_bf16.h>

typedef __hip_bfloat16 bf16;
typedef unsigned short u16;

#define NC 8192
#define NF 32768
#define DD 256
#define DE 128
#define KNN 16
#define FMAXV 3.402823466e+38f

__device__ __forceinline__ float bfbits2f(u16 u){
  union { unsigned u; float f; } x; x.u = ((unsigned)u) << 16; return x.f;
}

// ---------- decoder positions -> float4(x,y,z,|d|^2 * 0.5) ----------
// key: val = dd/2 - e.d  is a monotone transform of d2 = ee - 2 e.d + dd
__global__ __launch_bounds__(256) void k_pos4(const float* __restrict__ dpos,
                                              float4* __restrict__ pos4){
  int i = blockIdx.x * 256 + threadIdx.x;
  if (i < NC){
    float x = dpos[i * 3 + 0], y = dpos[i * 3 + 1], z = dpos[i * 3 + 2];
    float dd = __fadd_rn(__fadd_rn(__fmul_rn(x,x), __fmul_rn(y,y)), __fmul_rn(z,z));
    pos4[i] = make_float4(x, y, z, dd * 0.5f);
  }
}

// ---------- decoder tables: K=df@Wk^T+bk, V=df@Wv^T+bv (LDS only),
//            then Zd = K@Wq [*,128], Ud = V@W1a^T [*,128], bqK = K.bq ----------
__global__ __launch_bounds__(256) void k_dec(const float* __restrict__ df,
                                             const float* __restrict__ Wq, const float* __restrict__ bq,
                                             const float* __restrict__ Wk, const float* __restrict__ bk,
                                             const float* __restrict__ Wv, const float* __restrict__ bv,
                                             const float* __restrict__ W1,
                                             bf16* __restrict__ Zd, bf16* __restrict__ Ud,
                                             float* __restrict__ bqK){
  __shared__ float bufA[16 * 256];   // df staging, then K rows
  __shared__ float bufB[16 * 256];   // V rows
  int t = threadIdx.x;
  int g0 = blockIdx.x * 16;
  for (int r = 0; r < 16; ++r)
    bufA[r * 256 + t] = df[(size_t)(g0 + r) * 256 + t];
  __syncthreads();
  float accK[16], accV[16];
  #pragma unroll
  for (int p = 0; p < 16; ++p){ accK[p] = 0.f; accV[p] = 0.f; }
  const float4* wkp = (const float4*)(Wk + (size_t)t * 256);
  const float4* wvp = (const float4*)(Wv + (size_t)t * 256);
  const float4* A4 = (const float4*)bufA;
  for (int c4 = 0; c4 < 64; ++c4){
    float4 wk = wkp[c4], wv = wvp[c4];
    #pragma unroll
    for (int p = 0; p < 16; ++p){
      float4 a = A4[p * 64 + c4];
      accK[p] += wk.x*a.x + wk.y*a.y + wk.z*a.z + wk.w*a.w;
      accV[p] += wv.x*a.x + wv.y*a.y + wv.z*a.z + wv.w*a.w;
    }
  }
  float bkj = bk[t];
  float bvj = bv[t];
  __syncthreads();                       // all df reads done; bufA can be overwritten
  #pragma unroll
  for (int p = 0; p < 16; ++p){
    bufA[p * 256 + t] = accK[p] + bkj;   // K
    bufB[p * 256 + t] = accV[p] + bvj;   // V
  }
  __syncthreads();
  // bqK (16 threads; bq is typically zero but keep exact)
  if (t < 16){
    float s = 0.f;
    for (int j = 0; j < 256; ++j) s += bq[j] * bufA[t * 256 + j];
    bqK[g0 + t] = s;
  }
  // Zd[p][c] = sum_j K[p][j] * Wq[j][c]   (c = t&127, 8 points per thread)
  {
    int c = t & 127, pg = t >> 7;
    float acc[8];
    #pragma unroll
    for (int pp = 0; pp < 8; ++pp) acc[pp] = 0.f;
    for (int j0 = 0; j0 < 256; j0 += 8){
      float w[8];
      #pragma unroll
      for (int jj = 0; jj < 8; ++jj)
        w[jj] = Wq[(size_t)(j0 + jj) * 128 + c];
      #pragma unroll
      for (int pp = 0; pp < 8; ++pp){
        float4 a = ((const float4*)bufA)[(pg * 8 + pp) * 64 + (j0 >> 2)];
        float4 b = ((const float4*)bufA)[(pg * 8 + pp) * 64 + (j0 >> 2) + 1];
        acc[pp] += w[0]*a.x + w[1]*a.y + w[2]*a.z + w[3]*a.w
                 + w[4]*b.x + w[5]*b.y + w[6]*b.z + w[7]*b.w;
      }
    }
    #pragma unroll
    for (int pp = 0; pp < 8; ++pp)
      Zd[(size_t)(g0 + pg * 8 + pp) * 128 + c] = __float2bfloat16(acc[pp]);
  }
  // Ud[p][h] = sum_c W1[h][c] * V[p][c]   (h = t&127, first 256 cols of W1)
  {
    int h = t & 127, pg = t >> 7;
    float acc[8];
    #pragma unroll
    for (int pp = 0; pp < 8; ++pp) acc[pp] = 0.f;
    const float4* w1r = (const float4*)(W1 + (size_t)h * 384);
    for (int c4 = 0; c4 < 64; ++c4){
      float4 w = w1r[c4];
      #pragma unroll
      for (int pp = 0; pp < 8; ++pp){
        float4 a = ((const float4*)bufB)[(pg * 8 + pp) * 64 + c4];
        acc[pp] += w.x*a.x + w.y*a.y + w.z*a.z + w.w*a.w;
      }
    }
    #pragma unroll
    for (int pp = 0; pp < 8; ++pp)
      Ud[(size_t)(g0 + pg * 8 + pp) * 128 + h] = __float2bfloat16(acc[pp]);
  }
}

// ---------- fused: two-pass top-16 KNN + attention (via Zd) + hidden agg (via Ud) ----------
// Pass A: per-lane min of val (no cross-lane). Bitonic-sort the 64 lane minima;
// tau0 = 17th smallest lane-min >= true 16th-smallest val (16 smallest lane minima
// are 16 distinct candidates). Pass B: rescan, serial-insert only val<=tau0 (~20 hits).
__global__ __launch_bounds__(256) void k_attn(const float* __restrict__ epos,
                                              const float4* __restrict__ pos4,
                                              const float* __restrict__ ef,
                                              const bf16* __restrict__ Zd,
                                              const bf16* __restrict__ Ud,
                                              const float* __restrict__ bqK,
                                              bf16* __restrict__ hagg){
  __shared__ float4 stage[1024];
  int t = threadIdx.x;
  int lane = t & 63;
  int n = blockIdx.x * 4 + (t >> 6);
  float ex = epos[n * 3 + 0], ey = epos[n * 3 + 1], ez = epos[n * 3 + 2];

  // ---- PASS A: per-lane minimum of val = dd/2 - e.d
  float vmin = FMAXV;
  for (int ch = 0; ch < 8; ++ch){
    __syncthreads();
    #pragma unroll
    for (int u = 0; u < 4; ++u)
      stage[u * 256 + t] = pos4[ch * 1024 + u * 256 + t];
    __syncthreads();
    #pragma unroll 4
    for (int s = 0; s < 16; ++s){
      float4 P = stage[s * 64 + lane];
      float ed = fmaf(ez, P.z, fmaf(ey, P.y, ex * P.x));
      float val = P.w - ed;
      vmin = fminf(vmin, val);
    }
  }
  // ---- bitonic sort of 64 lane minima (ascending across lanes)
  {
    float v = vmin;
    #pragma unroll
    for (int k = 2; k <= 64; k <<= 1){
      #pragma unroll
      for (int j = k >> 1; j > 0; j >>= 1){
        float p = __shfl_xor(v, j);
        bool asc = ((lane & k) == 0);
        bool lower = ((lane & j) == 0);
        v = (lower == asc) ? fminf(v, p) : fmaxf(v, p);
      }
    }
    vmin = v;
  }
  float tau0 = __shfl(vmin, 16);   // 17th smallest: provably >= true 16th, +1 rank slack

  // ---- PASS B: filtered exact sorted-insert
  float topv = FMAXV;
  int   topi = 0;
  float tau  = FMAXV;
  for (int ch = 0; ch < 8; ++ch){
    __syncthreads();
    #pragma unroll
    for (int u = 0; u < 4; ++u)
      stage[u * 256 + t] = pos4[ch * 1024 + u * 256 + t];
    __syncthreads();
    for (int s = 0; s < 16; ++s){
      float4 P = stage[s * 64 + lane];
      float ed = fmaf(ez, P.z, fmaf(ey, P.y, ex * P.x));
      float val = P.w - ed;
      int idx = ch * 1024 + s * 64 + lane;
      unsigned long long m = __ballot((val <= tau0) && (val < tau));
      while (m){
        int src = __ffsll((unsigned long long)m) - 1;
        m &= m - 1;
        float v  = __shfl(val, src);
        int   vi = __shfl(idx, src);
        if (v < tau){
          int pos = __popcll(__ballot((lane < KNN) && (topv <= v)));
          float sv = __shfl_up(topv, 1);
          int   si = __shfl_up(topi, 1);
          if (lane < KNN){
            if (lane == pos){ topv = v; topi = vi; }
            else if (lane > pos){ topv = sv; topi = si; }
          }
          tau = __shfl(topv, KNN - 1);
        }
      }
    }
  }

  // scores: sc_k = (ef[n] . Zd[ik] + bqK[ik]) / 16
  float2 eu = *(const float2*)(ef + (size_t)n * 128 + lane * 2);
  float sc = -FMAXV;
  #pragma unroll
  for (int k = 0; k < KNN; ++k){
    int ik = __shfl(topi, k);
    ushort2 zu = *(const ushort2*)((const u16*)Zd + (size_t)ik * 128 + lane * 2);
    float p = eu.x * bfbits2f(zu.x) + eu.y * bfbits2f(zu.y);
    #pragma unroll
    for (int off = 32; off >= 1; off >>= 1) p += __shfl_xor(p, off);
    float bz = bqK[ik];
    if (lane == k) sc = (p + bz) * (1.0f / 16.0f);
  }
  // softmax over lanes 0..15
  float mx = sc;
  #pragma unroll
  for (int off = 8; off >= 1; off >>= 1) mx = fmaxf(mx, __shfl_xor(mx, off));
  float e = (lane < KNN) ? __expf(sc - mx) : 0.f;
  float l = e;
  #pragma unroll
  for (int off = 8; off >= 1; off >>= 1) l += __shfl_xor(l, off);
  float wgt = (lane < KNN) ? (e / l) : 0.f;

  // hidden-space aggregation: hagg = sum_k w_k * Ud[ik]  (2 channels per lane)
  float a0 = 0.f, a1 = 0.f;
  #pragma unroll
  for (int k = 0; k < KNN; ++k){
    int ik = __shfl(topi, k);
    float wk = __shfl(wgt, k);
    ushort2 uu = *(const ushort2*)((const u16*)Ud + (size_t)ik * 128 + lane * 2);
    a0 = fmaf(wk, bfbits2f(uu.x), a0);
    a1 = fmaf(wk, bfbits2f(uu.y), a1);
  }
  bf16* hr = hagg + (size_t)n * 128 + lane * 2;
  hr[0] = __float2bfloat16(a0);
  hr[1] = __float2bfloat16(a1);
}

// ---------- MLP: h = relu(hagg + W1e@ef + b1); up = W2@h + b2; LayerNorm ----------
__global__ __launch_bounds__(256) void k_mlp(const bf16* __restrict__ hagg, const float* __restrict__ ef,
                                             const float* __restrict__ W1, const float* __restrict__ b1,
                                             const float* __restrict__ W2, const float* __restrict__ b2,
                                             const float* __restrict__ lng, const float* __restrict__ lnb,
                                             float* __restrict__ out){
  __shared__ float efs[16 * 128];
  __shared__ float hgs[16 * 128];
  __shared__ float hbuf[16 * 128];
  __shared__ float ubuf[16 * 128];
  __shared__ float stats[32];
  int t = threadIdx.x;
  int n0 = blockIdx.x * 16;
  for (int f = t; f < 2048; f += 256){
    int r = f >> 7, c = f & 127;
    efs[f] = ef[(size_t)(n0 + r) * 128 + c];
    hgs[f] = __bfloat162float(hagg[(size_t)(n0 + r) * 128 + c]);
  }
  __syncthreads();
  int jg = t & 63, pg = t >> 6;
  int j0 = jg * 2, p0 = pg * 4;
  float acc[2][4];
  #pragma unroll
  for (int a = 0; a < 2; ++a)
    #pragma unroll
    for (int p = 0; p < 4; ++p) acc[a][p] = 0.f;
  const float4* w1a = (const float4*)(W1 + (size_t)j0 * 384 + 256);
  const float4* w1b = (const float4*)(W1 + (size_t)(j0 + 1) * 384 + 256);
  const float4* efs4 = (const float4*)efs;
  for (int c4 = 0; c4 < 32; ++c4){
    float4 wa = w1a[c4], wb = w1b[c4];
    #pragma unroll
    for (int p = 0; p < 4; ++p){
      float4 x = efs4[(p0 + p) * 32 + c4];
      acc[0][p] += wa.x*x.x + wa.y*x.y + wa.z*x.z + wa.w*x.w;
      acc[1][p] += wb.x*x.x + wb.y*x.y + wb.z*x.z + wb.w*x.w;
    }
  }
  float b1a = b1[j0], b1b = b1[j0 + 1];
  #pragma unroll
  for (int p = 0; p < 4; ++p){
    hbuf[(p0 + p) * 128 + j0]     = fmaxf(acc[0][p] + b1a + hgs[(p0 + p) * 128 + j0],     0.f);
    hbuf[(p0 + p) * 128 + j0 + 1] = fmaxf(acc[1][p] + b1b + hgs[(p0 + p) * 128 + j0 + 1], 0.f);
  }
  __syncthreads();
  float acc2[2][4];
  #pragma unroll
  for (int a = 0; a < 2; ++a)
    #pragma unroll
    for (int p = 0; p < 4; ++p) acc2[a][p] = 0.f;
  const float4* w2a = (const float4*)(W2 + (size_t)j0 * 128);
  const float4* w2b = (const float4*)(W2 + (size_t)(j0 + 1) * 128);
  const float4* hb4 = (const float4*)hbuf;
  for (int c4 = 0; c4 < 32; ++c4){
    float4 wa = w2a[c4], wb = w2b[c4];
    #pragma unroll
    for (int p = 0; p < 4; ++p){
      float4 x = hb4[(p0 + p) * 32 + c4];
      acc2[0][p] += wa.x*x.x + wa.y*x.y + wa.z*x.z + wa.w*x.w;
      acc2[1][p] += wb.x*x.x + wb.y*x.y + wb.z*x.z + wb.w*x.w;
    }
  }
  float b2a = b2[j0], b2b = b2[j0 + 1];
  float u[2][4];
  #pragma unroll
  for (int p = 0; p < 4; ++p){
    u[0][p] = acc2[0][p] + b2a;
    u[1][p] = acc2[1][p] + b2b;
    ubuf[(p0 + p) * 128 + j0]     = u[0][p];
    ubuf[(p0 + p) * 128 + j0 + 1] = u[1][p];
  }
  __syncthreads();
  {
    int p = t >> 4, qi = t & 15;
    const float* ub = &ubuf[p * 128 + qi * 8];
    float s = 0.f, s2 = 0.f;
    #pragma unroll
    for (int e2i = 0; e2i < 8; ++e2i){ float v = ub[e2i]; s += v; s2 += v * v; }
    #pragma unroll
    for (int off = 1; off < 16; off <<= 1){ s += __shfl_xor(s, off); s2 += __shfl_xor(s2, off); }
    if (qi == 0){
      float mu = s * (1.f / 128.f);
      float var = s2 * (1.f / 128.f) - mu * mu;
      stats[p] = mu;
      stats[16 + p] = rsqrtf(fmaxf(var, 0.f) + 1e-5f);
    }
  }
  __syncthreads();
  float ga = lng[j0], gb = lng[j0 + 1];
  float ba = lnb[j0], bbv = lnb[j0 + 1];
  #pragma unroll
  for (int p = 0; p < 4; ++p){
    float mu = stats[p0 + p], rs = stats[16 + p0 + p];
    out[(size_t)(n0 + p0 + p) * 128 + j0]     = (u[0][p] - mu) * rs * ga + ba;
    out[(size_t)(n0 + p0 + p) * 128 + j0 + 1] = (u[1][p] - mu) * rs * gb + bbv;
  }
}

// ---------- passthrough outputs: encoder_pos and labels ----------
__global__ __launch_bounds__(256) void k_tail(const float* __restrict__ epos,
                                              const int* __restrict__ lab,
                                              float* __restrict__ out){
  int i = blockIdx.x * 256 + threadIdx.x;
  if (i < NF){
    float* op = out + (size_t)NF * 128;
    op[i * 3 + 0] = epos[i * 3 + 0];
    op[i * 3 + 1] = epos[i * 3 + 1];
    op[i * 3 + 2] = epos[i * 3 + 2];
    out[(size_t)NF * 128 + (size_t)NF * 3 + i] = (float)lab[i];
  }
}

extern "C" void kernel_launch(void* const* d_in, const int* in_sizes, int n_in,
                              void* d_out, int out_size, void* d_ws, size_t ws_size,
                              hipStream_t stream){
  const float* df   = (const float*)d_in[0];
  const float* dpos = (const float*)d_in[1];
  const float* ef   = (const float*)d_in[2];
  const float* epos = (const float*)d_in[3];
  const int*   lab  = (const int*)d_in[4];
  const float* Wq = (const float*)d_in[5];
  const float* bq = (const float*)d_in[6];
  const float* Wk = (const float*)d_in[7];
  const float* bk = (const float*)d_in[8];
  const float* Wv = (const float*)d_in[9];
  const float* bv = (const float*)d_in[10];
  const float* W1 = (const float*)d_in[11];
  const float* b1 = (const float*)d_in[12];
  const float* W2 = (const float*)d_in[13];
  const float* b2 = (const float*)d_in[14];
  const float* lng = (const float*)d_in[15];
  const float* lnb = (const float*)d_in[16];
  float* out = (float*)d_out;

  // workspace layout (total ~12.2 MB)
  char* wsb = (char*)d_ws;
  float4* pos4 = (float4*)wsb;                        // 131072 B
  bf16*  Zd   = (bf16*)(wsb + 131072);                // 2 MB
  bf16*  Ud   = (bf16*)(wsb + 131072 + 2097152);      // 2 MB
  float* bqK  = (float*)(wsb + 131072 + 4194304);     // 32 KB
  bf16*  hagg = (bf16*)(wsb + 131072 + 4194304 + 32768); // 8 MB

  k_pos4 <<<NC / 256, 256, 0, stream>>>(dpos, pos4);
  k_dec  <<<NC / 16,  256, 0, stream>>>(df, Wq, bq, Wk, bk, Wv, bv, W1, Zd, Ud, bqK);
  k_attn <<<NF / 4,   256, 0, stream>>>(epos, pos4, ef, Zd, Ud, bqK, hagg);
  k_mlp  <<<NF / 16,  256, 0, stream>>>(hagg, ef, W1, b1, W2, b2, lng, lnb, out);
  k_tail <<<NF / 256, 256, 0, stream>>>(epos, lab, out);
  (void)in_sizes; (void)n_in; (void)out_size; (void)ws_size;
}

// Round 5
// 373.989 us; speedup vs baseline: 1.7260x; 1.4407x over previous
//
#include <hip/hip_runtime.h>
#include <hip/hip_bf16.h>

typedef __hip_bfloat16 bf16;
typedef unsigned short u16;

#define NC 8192
#define NF 32768
#define DD 256
#define DE 128
#define KNN 16
#define FMAXV 3.402823466e+38f

__device__ __forceinline__ float bfbits2f(u16 u){
  union { unsigned u; float f; } x; x.u = ((unsigned)u) << 16; return x.f;
}

// ---------- one-time prep: pos4 (x,y,z,|d|^2/2) + weight swizzles ----------
// Swizzled layouts put the float4 chunk that lane L reads at [chunk*width + L]
// so hot-loop weight loads are perfectly coalesced (they were 64-way scattered).
__global__ __launch_bounds__(256) void k_prep(const float* __restrict__ dpos,
                                              const float* __restrict__ Wk,
                                              const float* __restrict__ Wv,
                                              const float* __restrict__ W1,
                                              const float* __restrict__ W2,
                                              float4* __restrict__ pos4,
                                              float4* __restrict__ WkS,
                                              float4* __restrict__ WvS,
                                              float4* __restrict__ W1aS,
                                              float4* __restrict__ W1eSa,
                                              float4* __restrict__ W1eSb,
                                              float4* __restrict__ W2Sa,
                                              float4* __restrict__ W2Sb){
  int g = blockIdx.x * 256 + threadIdx.x;
  if (g < 8192){
    float x = dpos[g * 3 + 0], y = dpos[g * 3 + 1], z = dpos[g * 3 + 2];
    float dd = __fadd_rn(__fadd_rn(__fmul_rn(x,x), __fmul_rn(y,y)), __fmul_rn(z,z));
    pos4[g] = make_float4(x, y, z, dd * 0.5f);
  } else if (g < 24576){
    int f = g - 8192; int c4 = f >> 8, t = f & 255;
    WkS[f] = ((const float4*)(Wk + (size_t)t * 256))[c4];
  } else if (g < 40960){
    int f = g - 24576; int c4 = f >> 8, t = f & 255;
    WvS[f] = ((const float4*)(Wv + (size_t)t * 256))[c4];
  } else if (g < 49152){
    int f = g - 40960; int c4 = f >> 7, h = f & 127;
    W1aS[f] = ((const float4*)(W1 + (size_t)h * 384))[c4];
  } else if (g < 51200){
    int f = g - 49152; int c4 = f >> 6, jg = f & 63;
    W1eSa[f] = ((const float4*)(W1 + (size_t)(2 * jg) * 384 + 256))[c4];
  } else if (g < 53248){
    int f = g - 51200; int c4 = f >> 6, jg = f & 63;
    W1eSb[f] = ((const float4*)(W1 + (size_t)(2 * jg + 1) * 384 + 256))[c4];
  } else if (g < 55296){
    int f = g - 53248; int c4 = f >> 6, jg = f & 63;
    W2Sa[f] = ((const float4*)(W2 + (size_t)(2 * jg) * 128))[c4];
  } else if (g < 57344){
    int f = g - 55296; int c4 = f >> 6, jg = f & 63;
    W2Sb[f] = ((const float4*)(W2 + (size_t)(2 * jg + 1) * 128))[c4];
  }
}

// ---------- decoder tables: K=df@Wk^T+bk, V=df@Wv^T+bv (LDS only),
//            then Zd = K@Wq [*,128], Ud = V@W1a^T [*,128], bqK = K.bq ----------
__global__ __launch_bounds__(256) void k_dec(const float* __restrict__ df,
                                             const float* __restrict__ Wq, const float* __restrict__ bq,
                                             const float4* __restrict__ WkS, const float* __restrict__ bk,
                                             const float4* __restrict__ WvS, const float* __restrict__ bv,
                                             const float4* __restrict__ W1aS,
                                             bf16* __restrict__ Zd, bf16* __restrict__ Ud,
                                             float* __restrict__ bqK){
  __shared__ float bufA[16 * 256];   // df staging, then K rows
  __shared__ float bufB[16 * 256];   // V rows
  int t = threadIdx.x;
  int g0 = blockIdx.x * 16;
  for (int r = 0; r < 16; ++r)
    bufA[r * 256 + t] = df[(size_t)(g0 + r) * 256 + t];
  __syncthreads();
  float accK[16], accV[16];
  #pragma unroll
  for (int p = 0; p < 16; ++p){ accK[p] = 0.f; accV[p] = 0.f; }
  const float4* A4 = (const float4*)bufA;
  for (int c4 = 0; c4 < 64; ++c4){
    float4 wk = WkS[c4 * 256 + t];   // coalesced swizzled load
    float4 wv = WvS[c4 * 256 + t];
    #pragma unroll
    for (int p = 0; p < 16; ++p){
      float4 a = A4[p * 64 + c4];
      accK[p] += wk.x*a.x + wk.y*a.y + wk.z*a.z + wk.w*a.w;
      accV[p] += wv.x*a.x + wv.y*a.y + wv.z*a.z + wv.w*a.w;
    }
  }
  float bkj = bk[t];
  float bvj = bv[t];
  __syncthreads();                       // all df reads done; bufA can be overwritten
  #pragma unroll
  for (int p = 0; p < 16; ++p){
    bufA[p * 256 + t] = accK[p] + bkj;   // K
    bufB[p * 256 + t] = accV[p] + bvj;   // V
  }
  __syncthreads();
  // bqK (16 threads; bq is typically zero but keep exact)
  if (t < 16){
    float s = 0.f;
    for (int j = 0; j < 256; ++j) s += bq[j] * bufA[t * 256 + j];
    bqK[g0 + t] = s;
  }
  // Zd[p][c] = sum_j K[p][j] * Wq[j][c]   (c = t&127, 8 points per thread)
  {
    int c = t & 127, pg = t >> 7;
    float acc[8];
    #pragma unroll
    for (int pp = 0; pp < 8; ++pp) acc[pp] = 0.f;
    for (int j0 = 0; j0 < 256; j0 += 8){
      float w[8];
      #pragma unroll
      for (int jj = 0; jj < 8; ++jj)
        w[jj] = Wq[(size_t)(j0 + jj) * 128 + c];
      #pragma unroll
      for (int pp = 0; pp < 8; ++pp){
        float4 a = ((const float4*)bufA)[(pg * 8 + pp) * 64 + (j0 >> 2)];
        float4 b = ((const float4*)bufA)[(pg * 8 + pp) * 64 + (j0 >> 2) + 1];
        acc[pp] += w[0]*a.x + w[1]*a.y + w[2]*a.z + w[3]*a.w
                 + w[4]*b.x + w[5]*b.y + w[6]*b.z + w[7]*b.w;
      }
    }
    #pragma unroll
    for (int pp = 0; pp < 8; ++pp)
      Zd[(size_t)(g0 + pg * 8 + pp) * 128 + c] = __float2bfloat16(acc[pp]);
  }
  // Ud[p][h] = sum_c W1[h][c] * V[p][c]   (h = t&127, first 256 cols of W1)
  {
    int h = t & 127, pg = t >> 7;
    float acc[8];
    #pragma unroll
    for (int pp = 0; pp < 8; ++pp) acc[pp] = 0.f;
    for (int c4 = 0; c4 < 64; ++c4){
      float4 w = W1aS[c4 * 128 + h];   // coalesced swizzled load
      #pragma unroll
      for (int pp = 0; pp < 8; ++pp){
        float4 a = ((const float4*)bufB)[(pg * 8 + pp) * 64 + c4];
        acc[pp] += w.x*a.x + w.y*a.y + w.z*a.z + w.w*a.w;
      }
    }
    #pragma unroll
    for (int pp = 0; pp < 8; ++pp)
      Ud[(size_t)(g0 + pg * 8 + pp) * 128 + h] = __float2bfloat16(acc[pp]);
  }
}

// ---------- fused KNN + attention: candidates split across the block's 4 waves ----------
// Each wave scans 2048 candidates for all 4 of the block's points (amortizes each
// L2 read over 4 points, no LDS staging). Bound tau0 = 17th smallest of the union
// of each wave's 16 smallest lane-minima (provable upper bound on the true 16th).
// Pass B appends the ~20 candidates <= tau0 via LDS atomics; exact (val,idx) sort.
__global__ __launch_bounds__(256) void k_attn(const float* __restrict__ epos,
                                              const float4* __restrict__ pos4,
                                              const float* __restrict__ ef,
                                              const bf16* __restrict__ Zd,
                                              const bf16* __restrict__ Ud,
                                              const float* __restrict__ bqK,
                                              bf16* __restrict__ hagg){
  __shared__ float smin[4 * 64];
  __shared__ float tauLDS[4];
  __shared__ int   cnt[4];
  __shared__ float lval[4][64];
  __shared__ int   lidx[4][64];

  int t = threadIdx.x, lane = t & 63, w = t >> 6;
  int n0 = blockIdx.x * 4;
  float ex[4], ey[4], ez[4];
  #pragma unroll
  for (int p = 0; p < 4; ++p){
    ex[p] = epos[(n0 + p) * 3 + 0];
    ey[p] = epos[(n0 + p) * 3 + 1];
    ez[p] = epos[(n0 + p) * 3 + 2];
  }
  const float4* base = pos4 + w * 2048;

  // ---- PASS A: per-lane minima of val = dd/2 - e.d over this wave's 2048
  float vmin[4] = {FMAXV, FMAXV, FMAXV, FMAXV};
  #pragma unroll 4
  for (int s = 0; s < 32; ++s){
    float4 P = base[s * 64 + lane];
    #pragma unroll
    for (int p = 0; p < 4; ++p){
      float ed = fmaf(ez[p], P.z, fmaf(ey[p], P.y, ex[p] * P.x));
      vmin[p] = fminf(vmin[p], P.w - ed);
    }
  }
  // 4 bitonic sorts (ascending across lanes)
  #pragma unroll
  for (int k = 2; k <= 64; k <<= 1){
    #pragma unroll
    for (int j = k >> 1; j > 0; j >>= 1){
      bool keepmin = ((lane & j) == 0) == ((lane & k) == 0);
      #pragma unroll
      for (int p = 0; p < 4; ++p){
        float pv = __shfl_xor(vmin[p], j);
        vmin[p] = keepmin ? fminf(vmin[p], pv) : fmaxf(vmin[p], pv);
      }
    }
  }
  if (lane < 16){
    #pragma unroll
    for (int p = 0; p < 4; ++p) smin[p * 64 + w * 16 + lane] = vmin[p];
  }
  if (t < 4) cnt[t] = 0;
  __syncthreads();
  // wave w: sort the 64-value union for point w; tau0 = 17th smallest
  {
    float v = smin[w * 64 + lane];
    #pragma unroll
    for (int k = 2; k <= 64; k <<= 1){
      #pragma unroll
      for (int j = k >> 1; j > 0; j >>= 1){
        float pv = __shfl_xor(v, j);
        bool keepmin = ((lane & j) == 0) == ((lane & k) == 0);
        v = keepmin ? fminf(v, pv) : fmaxf(v, pv);
      }
    }
    if (lane == 16) tauLDS[w] = v;
  }
  __syncthreads();
  float tau0[4];
  #pragma unroll
  for (int p = 0; p < 4; ++p) tau0[p] = tauLDS[p];

  // ---- PASS B: filtered append (rare), identical FP ops as pass A
  #pragma unroll 2
  for (int s = 0; s < 32; ++s){
    float4 P = base[s * 64 + lane];
    int cand = w * 2048 + s * 64 + lane;
    #pragma unroll
    for (int p = 0; p < 4; ++p){
      float ed = fmaf(ez[p], P.z, fmaf(ey[p], P.y, ex[p] * P.x));
      float val = P.w - ed;
      if (val <= tau0[p]){
        int slot = atomicAdd(&cnt[p], 1);
        if (slot < 64){ lval[p][slot] = val; lidx[p][slot] = cand; }
      }
    }
  }
  __syncthreads();

  // ---- wave w finalizes point w: exact (val,idx) bitonic sort, top-16 in lanes 0..15
  int n = n0 + w;
  int c = cnt[w]; if (c > 64) c = 64;
  float v  = (lane < c) ? lval[w][lane] : FMAXV;
  int   id = (lane < c) ? lidx[w][lane] : 0x7fffffff;
  #pragma unroll
  for (int k = 2; k <= 64; k <<= 1){
    #pragma unroll
    for (int j = k >> 1; j > 0; j >>= 1){
      float pv  = __shfl_xor(v, j);
      int   pid = __shfl_xor(id, j);
      bool keepmin = ((lane & j) == 0) == ((lane & k) == 0);
      bool pless = (pv < v) || (pv == v && pid < id);
      bool take = keepmin ? pless : !pless;
      if (take){ v = pv; id = pid; }
    }
  }
  int topi = id;

  // scores: sc_k = (ef[n] . Zd[ik] + bqK[ik]) / 16
  float2 eu = *(const float2*)(ef + (size_t)n * 128 + lane * 2);
  float sc = -FMAXV;
  #pragma unroll
  for (int k = 0; k < KNN; ++k){
    int ik = __shfl(topi, k);
    ushort2 zu = *(const ushort2*)((const u16*)Zd + (size_t)ik * 128 + lane * 2);
    float p = eu.x * bfbits2f(zu.x) + eu.y * bfbits2f(zu.y);
    #pragma unroll
    for (int off = 32; off >= 1; off >>= 1) p += __shfl_xor(p, off);
    float bz = bqK[ik];
    if (lane == k) sc = (p + bz) * (1.0f / 16.0f);
  }
  // softmax over lanes 0..15
  float mx = sc;
  #pragma unroll
  for (int off = 8; off >= 1; off >>= 1) mx = fmaxf(mx, __shfl_xor(mx, off));
  float e = (lane < KNN) ? __expf(sc - mx) : 0.f;
  float l = e;
  #pragma unroll
  for (int off = 8; off >= 1; off >>= 1) l += __shfl_xor(l, off);
  float wgt = (lane < KNN) ? (e / l) : 0.f;

  // hidden-space aggregation: hagg = sum_k w_k * Ud[ik]  (2 channels per lane)
  float a0 = 0.f, a1 = 0.f;
  #pragma unroll
  for (int k = 0; k < KNN; ++k){
    int ik = __shfl(topi, k);
    float wk = __shfl(wgt, k);
    ushort2 uu = *(const ushort2*)((const u16*)Ud + (size_t)ik * 128 + lane * 2);
    a0 = fmaf(wk, bfbits2f(uu.x), a0);
    a1 = fmaf(wk, bfbits2f(uu.y), a1);
  }
  bf16* hr = hagg + (size_t)n * 128 + lane * 2;
  hr[0] = __float2bfloat16(a0);
  hr[1] = __float2bfloat16(a1);
}

// ---------- MLP (+ fused passthrough tail): h=relu(hagg+W1e@ef+b1); up=W2@h+b2; LN ----------
__global__ __launch_bounds__(256) void k_mlp(const bf16* __restrict__ hagg, const float* __restrict__ ef,
                                             const float4* __restrict__ W1eSa, const float4* __restrict__ W1eSb,
                                             const float* __restrict__ b1,
                                             const float4* __restrict__ W2Sa, const float4* __restrict__ W2Sb,
                                             const float* __restrict__ b2,
                                             const float* __restrict__ lng, const float* __restrict__ lnb,
                                             const float* __restrict__ epos, const int* __restrict__ lab,
                                             float* __restrict__ out){
  __shared__ float efs[16 * 128];
  __shared__ float hgs[16 * 128];
  __shared__ float hbuf[16 * 128];
  __shared__ float ubuf[16 * 128];
  __shared__ float stats[32];
  int t = threadIdx.x;
  int n0 = blockIdx.x * 16;
  // fused tail passthrough (grid 2048*256 >= NF)
  {
    int gid = blockIdx.x * 256 + t;
    if (gid < NF){
      float* op = out + (size_t)NF * 128;
      op[gid * 3 + 0] = epos[gid * 3 + 0];
      op[gid * 3 + 1] = epos[gid * 3 + 1];
      op[gid * 3 + 2] = epos[gid * 3 + 2];
      out[(size_t)NF * 128 + (size_t)NF * 3 + gid] = (float)lab[gid];
    }
  }
  for (int f = t; f < 2048; f += 256){
    int r = f >> 7, c = f & 127;
    efs[f] = ef[(size_t)(n0 + r) * 128 + c];
    hgs[f] = __bfloat162float(hagg[(size_t)(n0 + r) * 128 + c]);
  }
  __syncthreads();
  int jg = t & 63, pg = t >> 6;
  int j0 = jg * 2, p0 = pg * 4;
  float acc[2][4];
  #pragma unroll
  for (int a = 0; a < 2; ++a)
    #pragma unroll
    for (int p = 0; p < 4; ++p) acc[a][p] = 0.f;
  const float4* efs4 = (const float4*)efs;
  for (int c4 = 0; c4 < 32; ++c4){
    float4 wa = W1eSa[c4 * 64 + jg], wb = W1eSb[c4 * 64 + jg];   // coalesced
    #pragma unroll
    for (int p = 0; p < 4; ++p){
      float4 x = efs4[(p0 + p) * 32 + c4];
      acc[0][p] += wa.x*x.x + wa.y*x.y + wa.z*x.z + wa.w*x.w;
      acc[1][p] += wb.x*x.x + wb.y*x.y + wb.z*x.z + wb.w*x.w;
    }
  }
  float b1a = b1[j0], b1b = b1[j0 + 1];
  #pragma unroll
  for (int p = 0; p < 4; ++p){
    hbuf[(p0 + p) * 128 + j0]     = fmaxf(acc[0][p] + b1a + hgs[(p0 + p) * 128 + j0],     0.f);
    hbuf[(p0 + p) * 128 + j0 + 1] = fmaxf(acc[1][p] + b1b + hgs[(p0 + p) * 128 + j0 + 1], 0.f);
  }
  __syncthreads();
  float acc2[2][4];
  #pragma unroll
  for (int a = 0; a < 2; ++a)
    #pragma unroll
    for (int p = 0; p < 4; ++p) acc2[a][p] = 0.f;
  const float4* hb4 = (const float4*)hbuf;
  for (int c4 = 0; c4 < 32; ++c4){
    float4 wa = W2Sa[c4 * 64 + jg], wb = W2Sb[c4 * 64 + jg];     // coalesced
    #pragma unroll
    for (int p = 0; p < 4; ++p){
      float4 x = hb4[(p0 + p) * 32 + c4];
      acc2[0][p] += wa.x*x.x + wa.y*x.y + wa.z*x.z + wa.w*x.w;
      acc2[1][p] += wb.x*x.x + wb.y*x.y + wb.z*x.z + wb.w*x.w;
    }
  }
  float b2a = b2[j0], b2b = b2[j0 + 1];
  float u[2][4];
  #pragma unroll
  for (int p = 0; p < 4; ++p){
    u[0][p] = acc2[0][p] + b2a;
    u[1][p] = acc2[1][p] + b2b;
    ubuf[(p0 + p) * 128 + j0]     = u[0][p];
    ubuf[(p0 + p) * 128 + j0 + 1] = u[1][p];
  }
  __syncthreads();
  {
    int p = t >> 4, qi = t & 15;
    const float* ub = &ubuf[p * 128 + qi * 8];
    float s = 0.f, s2 = 0.f;
    #pragma unroll
    for (int e2i = 0; e2i < 8; ++e2i){ float v = ub[e2i]; s += v; s2 += v * v; }
    #pragma unroll
    for (int off = 1; off < 16; off <<= 1){ s += __shfl_xor(s, off); s2 += __shfl_xor(s2, off); }
    if (qi == 0){
      float mu = s * (1.f / 128.f);
      float var = s2 * (1.f / 128.f) - mu * mu;
      stats[p] = mu;
      stats[16 + p] = rsqrtf(fmaxf(var, 0.f) + 1e-5f);
    }
  }
  __syncthreads();
  float ga = lng[j0], gb = lng[j0 + 1];
  float ba = lnb[j0], bbv = lnb[j0 + 1];
  #pragma unroll
  for (int p = 0; p < 4; ++p){
    float mu = stats[p0 + p], rs = stats[16 + p0 + p];
    out[(size_t)(n0 + p0 + p) * 128 + j0]     = (u[0][p] - mu) * rs * ga + ba;
    out[(size_t)(n0 + p0 + p) * 128 + j0 + 1] = (u[1][p] - mu) * rs * gb + bbv;
  }
}

extern "C" void kernel_launch(void* const* d_in, const int* in_sizes, int n_in,
                              void* d_out, int out_size, void* d_ws, size_t ws_size,
                              hipStream_t stream){
  const float* df   = (const float*)d_in[0];
  const float* dpos = (const float*)d_in[1];
  const float* ef   = (const float*)d_in[2];
  const float* epos = (const float*)d_in[3];
  const int*   lab  = (const int*)d_in[4];
  const float* Wq = (const float*)d_in[5];
  const float* bq = (const float*)d_in[6];
  const float* Wk = (const float*)d_in[7];
  const float* bk = (const float*)d_in[8];
  const float* Wv = (const float*)d_in[9];
  const float* bv = (const float*)d_in[10];
  const float* W1 = (const float*)d_in[11];
  const float* b1 = (const float*)d_in[12];
  const float* W2 = (const float*)d_in[13];
  const float* b2 = (const float*)d_in[14];
  const float* lng = (const float*)d_in[15];
  const float* lnb = (const float*)d_in[16];
  float* out = (float*)d_out;

  // workspace layout (~12.9 MB)
  char* wsb = (char*)d_ws;
  float4* pos4  = (float4*)(wsb);                    // 131072 B
  bf16*   Zd    = (bf16*)(wsb + 131072);             // 2 MB
  bf16*   Ud    = (bf16*)(wsb + 2228224);            // 2 MB
  float*  bqK   = (float*)(wsb + 4325376);           // 32 KB
  bf16*   hagg  = (bf16*)(wsb + 4358144);            // 8 MB
  float4* WkS   = (float4*)(wsb + 12746752);         // 256 KB
  float4* WvS   = (float4*)(wsb + 13008896);         // 256 KB
  float4* W1aS  = (float4*)(wsb + 13271040);         // 128 KB
  float4* W1eSa = (float4*)(wsb + 13402112);         // 32 KB
  float4* W1eSb = (float4*)(wsb + 13434880);         // 32 KB
  float4* W2Sa  = (float4*)(wsb + 13467648);         // 32 KB
  float4* W2Sb  = (float4*)(wsb + 13500416);         // 32 KB

  k_prep <<<224, 256, 0, stream>>>(dpos, Wk, Wv, W1, W2, pos4, WkS, WvS, W1aS, W1eSa, W1eSb, W2Sa, W2Sb);
  k_dec  <<<NC / 16, 256, 0, stream>>>(df, Wq, bq, WkS, bk, WvS, bv, W1aS, Zd, Ud, bqK);
  k_attn <<<NF / 4, 256, 0, stream>>>(epos, pos4, ef, Zd, Ud, bqK, hagg);
  k_mlp  <<<NF / 16, 256, 0, stream>>>(hagg, ef, W1eSa, W1eSb, b1, W2Sa, W2Sb, b2, lng, lnb, epos, lab, out);
  (void)in_sizes; (void)n_in; (void)out_size; (void)ws_size;
}